// Round 2
// baseline (593.455 us; speedup 1.0000x reference)
//
#include <hip/hip_runtime.h>
#include <hip/hip_bf16.h>
#include <math.h>

// Problem constants (reference: T,B,H = 1024,128,512; A,K,F = 128,32,31)
#define T_DIM 1024
#define B_DIM 128
#define H_DIM 512
#define A_DIM 128
#define K_DIM 32
#define F_DIM 31

// Workspace layout (float offsets). Total = 675840 floats = 2.70 MB.
#define WS_WCOMB 0              // [31][128] fused conv-filter x W_loc
#define WS_PQ    4096           // [128][128] query @ W_q
#define WS_SCORE 20480          // [B][T] scores, overwritten in-place by alignment
#define WS_PART  151552         // [8][B][H] context partials

#define KC 32                   // K-chunk of the score GEMM

// ---------------------------------------------------------------------------
// Prep: Wcomb[f][a] = sum_k filter[k,f]*W_loc[k,a]   (conv+proj fused!)
//       pq[b][a]    = sum_h query[b,h]*W_q[h,a]
// ---------------------------------------------------------------------------
__global__ __launch_bounds__(256) void prep_kernel(
    const float* __restrict__ query, const float* __restrict__ conv_filter,
    const float* __restrict__ W_loc, const float* __restrict__ W_q,
    float* __restrict__ ws)
{
  int gid = blockIdx.x * 256 + threadIdx.x;
  if (blockIdx.x < 16) {
    if (gid < F_DIM * A_DIM) {
      int f = gid >> 7, a = gid & 127;
      float s = 0.f;
      #pragma unroll
      for (int k = 0; k < K_DIM; ++k)
        s += conv_filter[k * F_DIM + f] * W_loc[k * A_DIM + a];
      ws[WS_WCOMB + gid] = s;
    }
  } else {
    int idx = gid - 16 * 256;          // 0..16383
    int b = idx >> 7, a = idx & 127;
    float s = 0.f;
    for (int h = 0; h < H_DIM; ++h)
      s += query[b * H_DIM + h] * W_q[h * A_DIM + a];
    ws[WS_PQ + idx] = s;
  }
}

// ---------------------------------------------------------------------------
// Score kernel: per block, 2 t-values x all 128 b x all 128 a.
//   acc = enc @ W_k  (K=512, chunked by 32)
//   acc += conv location term via Wcomb (31 taps)
//   score[t,b] = sum_a tanh(acc + pq[b,a]) * v[a]
// LDS: encT transposed+swizzled (b128 reads, <=2-way banks),
//      wkL group-stride-20 (conflict-free b128 reads), prev rows t0-15..t0+16.
// ---------------------------------------------------------------------------
__global__ __launch_bounds__(256, 2) void score_kernel(
    const float* __restrict__ enc, const float* __restrict__ wk,
    const float* __restrict__ prev, const float* __restrict__ ws,
    const float* __restrict__ vvec, float* __restrict__ score)
{
  __shared__ float encT[KC * 256];     // [h][row ^ ((h>>2)&3)<<3]
  __shared__ float wkL[KC * 160];      // [h][8 groups x stride 20, 16 used]
  __shared__ float prevL[32 * 128];    // rows t0-15 .. t0+16

  const int tid = threadIdx.x;
  const int t0 = blockIdx.x * 2;
  const int R0 = blockIdx.x * 256;     // flat (t*B+b) row base
  const int rg = tid >> 3;             // 0..31 -> rows rg*8..rg*8+7
  const int cg = tid & 7;              // 0..7  -> cols cg*16..cg*16+15
  const int a0 = cg << 4;

  float acc[8][16];
  #pragma unroll
  for (int r = 0; r < 8; ++r)
    #pragma unroll
    for (int c = 0; c < 16; ++c) acc[r][c] = 0.f;

  // stage prev rows (zero-padded conv boundary)
  #pragma unroll
  for (int it = 0; it < 4; ++it) {
    int seg = tid + it * 256;          // 0..1023 float4s
    int rr = seg >> 5;
    int c4 = (seg & 31) << 2;
    int t = t0 - 15 + rr;
    float4 val = make_float4(0.f, 0.f, 0.f, 0.f);
    if (t >= 0 && t < T_DIM) val = *(const float4*)(prev + t * B_DIM + c4);
    *(float4*)(prevL + rr * 128 + c4) = val;
  }

  for (int hc = 0; hc < H_DIM; hc += KC) {
    __syncthreads();
    // W_k chunk -> grouped layout (stride 20 breaks 16-stride bank conflicts)
    #pragma unroll
    for (int it = 0; it < 4; ++it) {
      int seg = tid + it * 256;        // float4 index 0..1023
      int h = seg >> 5;
      int g = (seg >> 2) & 7;
      int w = (seg & 3) << 2;
      float4 val = *(const float4*)(wk + (hc + h) * A_DIM + g * 16 + w);
      *(float4*)(wkL + h * 160 + g * 20 + w) = val;
    }
    // enc chunk -> transposed + swizzled
    #pragma unroll
    for (int it = 0; it < 8; ++it) {
      int row = it * 32 + (tid >> 3);
      int j = tid & 7;                 // h-quad
      float4 val = *(const float4*)(enc + (size_t)(R0 + row) * H_DIM + hc + (j << 2));
      int rsw = row ^ ((j & 3) << 3);  // swizzle bits [4:3] by (h>>2)&3
      encT[(j * 4 + 0) * 256 + rsw] = val.x;
      encT[(j * 4 + 1) * 256 + rsw] = val.y;
      encT[(j * 4 + 2) * 256 + rsw] = val.z;
      encT[(j * 4 + 3) * 256 + rsw] = val.w;
    }
    __syncthreads();
    #pragma unroll 4
    for (int h = 0; h < KC; ++h) {
      int q = (h >> 2) & 3;
      const float* wbase = wkL + h * 160 + cg * 20;
      float4 w0 = *(const float4*)(wbase);
      float4 w1 = *(const float4*)(wbase + 4);
      float4 w2 = *(const float4*)(wbase + 8);
      float4 w3 = *(const float4*)(wbase + 12);
      const float* ebase = encT + h * 256 + ((rg ^ q) << 3);
      float4 e0 = *(const float4*)(ebase);
      float4 e1 = *(const float4*)(ebase + 4);
      float wv[16] = {w0.x,w0.y,w0.z,w0.w, w1.x,w1.y,w1.z,w1.w,
                      w2.x,w2.y,w2.z,w2.w, w3.x,w3.y,w3.z,w3.w};
      float ev[8]  = {e0.x,e0.y,e0.z,e0.w, e1.x,e1.y,e1.z,e1.w};
      #pragma unroll
      for (int r = 0; r < 8; ++r)
        #pragma unroll
        for (int c = 0; c < 16; ++c)
          acc[r][c] = fmaf(ev[r], wv[c], acc[r][c]);
    }
  }

  // Location term: acc[r][c] += sum_f prev[t-15+f, b] * Wcomb[f, a]
  #pragma unroll 1
  for (int f = 0; f < F_DIM; ++f) {
    const float* wc = ws + WS_WCOMB + f * A_DIM + a0;
    float4 c0 = *(const float4*)(wc);
    float4 c1 = *(const float4*)(wc + 4);
    float4 c2 = *(const float4*)(wc + 8);
    float4 c3 = *(const float4*)(wc + 12);
    float cv[16] = {c0.x,c0.y,c0.z,c0.w, c1.x,c1.y,c1.z,c1.w,
                    c2.x,c2.y,c2.z,c2.w, c3.x,c3.y,c3.z,c3.w};
    #pragma unroll
    for (int r = 0; r < 8; ++r) {
      int row = rg * 8 + r;
      float p = prevL[((row >> 7) + f) * 128 + (row & 127)];
      #pragma unroll
      for (int c = 0; c < 16; ++c) acc[r][c] = fmaf(p, cv[c], acc[r][c]);
    }
  }

  // Epilogue: + pq, tanh, dot v, reduce over the 8 col-groups
  const float* vp = vvec + a0;
  float4 v0 = *(const float4*)(vp);
  float4 v1 = *(const float4*)(vp + 4);
  float4 v2 = *(const float4*)(vp + 8);
  float4 v3 = *(const float4*)(vp + 12);
  float vv[16] = {v0.x,v0.y,v0.z,v0.w, v1.x,v1.y,v1.z,v1.w,
                  v2.x,v2.y,v2.z,v2.w, v3.x,v3.y,v3.z,v3.w};
  float part[8];
  #pragma unroll
  for (int r = 0; r < 8; ++r) {
    int row = rg * 8 + r;
    int b = row & 127;
    const float* pqp = ws + WS_PQ + b * A_DIM + a0;
    float4 p0 = *(const float4*)(pqp);
    float4 p1 = *(const float4*)(pqp + 4);
    float4 p2 = *(const float4*)(pqp + 8);
    float4 p3 = *(const float4*)(pqp + 12);
    float pv[16] = {p0.x,p0.y,p0.z,p0.w, p1.x,p1.y,p1.z,p1.w,
                    p2.x,p2.y,p2.z,p2.w, p3.x,p3.y,p3.z,p3.w};
    float s = 0.f;
    #pragma unroll
    for (int c = 0; c < 16; ++c)
      s += tanhf(acc[r][c] + pv[c]) * vv[c];
    part[r] = s;
  }
  #pragma unroll
  for (int r = 0; r < 8; ++r) {
    float s = part[r];
    s += __shfl_xor(s, 1);
    s += __shfl_xor(s, 2);
    s += __shfl_xor(s, 4);
    if (cg == 0) {
      int row = rg * 8 + r;
      int b = row & 127;
      int t = t0 + (row >> 7);
      score[b * T_DIM + t] = s;   // [B][T] for coalesced softmax reads
    }
  }
}

// ---------------------------------------------------------------------------
// Softmax over t per batch b; writes alignment in-place ([B][T] in ws) and
// to d_out ([T][B], the reference layout).
// ---------------------------------------------------------------------------
__global__ __launch_bounds__(256) void softmax_kernel(
    float* __restrict__ score, float* __restrict__ out_align)
{
  __shared__ float red[8];
  int b = blockIdx.x, tid = threadIdx.x;
  float v0[4];
  #pragma unroll
  for (int i = 0; i < 4; ++i) v0[i] = score[b * T_DIM + tid + i * 256];
  float m = fmaxf(fmaxf(v0[0], v0[1]), fmaxf(v0[2], v0[3]));
  #pragma unroll
  for (int off = 1; off < 64; off <<= 1) m = fmaxf(m, __shfl_xor(m, off));
  if ((tid & 63) == 0) red[tid >> 6] = m;
  __syncthreads();
  m = fmaxf(fmaxf(red[0], red[1]), fmaxf(red[2], red[3]));
  float s = 0.f;
  #pragma unroll
  for (int i = 0; i < 4; ++i) { v0[i] = expf(v0[i] - m); s += v0[i]; }
  #pragma unroll
  for (int off = 1; off < 64; off <<= 1) s += __shfl_xor(s, off);
  if ((tid & 63) == 0) red[4 + (tid >> 6)] = s;
  __syncthreads();
  float inv = 1.f / (red[4] + red[5] + red[6] + red[7]);
  #pragma unroll
  for (int i = 0; i < 4; ++i) {
    float a = v0[i] * inv;
    int t = tid + i * 256;
    score[b * T_DIM + t] = a;      // alignment [B][T] for context kernel
    out_align[t * B_DIM + b] = a;  // alignment [T][B] output
  }
}

// ---------------------------------------------------------------------------
// Context: partial[tc][b][h] = sum_{t in chunk tc} align[t,b]*enc[t,b,h]
// 1024 blocks (b x 8 t-chunks) keep the whole chip busy; deterministic.
// ---------------------------------------------------------------------------
__global__ __launch_bounds__(256) void context_partial(
    const float* __restrict__ enc, const float* __restrict__ align_bt,
    float* __restrict__ partial)
{
  int b  = blockIdx.x >> 3;
  int tc = blockIdx.x & 7;
  int tid = threadIdx.x;
  float2 acc = make_float2(0.f, 0.f);
  const float* ab = align_bt + b * T_DIM + tc * 128;
  const float* ebase = enc + ((size_t)(tc * 128) * B_DIM + b) * H_DIM + tid * 2;
  #pragma unroll 4
  for (int t = 0; t < 128; ++t) {
    float a = ab[t];
    float2 e = *(const float2*)(ebase + (size_t)t * B_DIM * H_DIM);
    acc.x += a * e.x;
    acc.y += a * e.y;
  }
  *(float2*)(partial + ((size_t)tc * B_DIM + b) * H_DIM + tid * 2) = acc;
}

__global__ __launch_bounds__(256) void context_reduce(
    const float* __restrict__ partial, float* __restrict__ ctx)
{
  int idx = blockIdx.x * 256 + threadIdx.x;   // 0..65535 = b*512+h
  float s = 0.f;
  #pragma unroll
  for (int tc = 0; tc < 8; ++tc) s += partial[tc * (B_DIM * H_DIM) + idx];
  ctx[idx] = s;
}

// ---------------------------------------------------------------------------
extern "C" void kernel_launch(void* const* d_in, const int* in_sizes, int n_in,
                              void* d_out, int out_size, void* d_ws, size_t ws_size,
                              hipStream_t stream)
{
  const float* enc   = (const float*)d_in[0];  // [T,B,H]
  const float* query = (const float*)d_in[1];  // [B,H]
  const float* prev  = (const float*)d_in[2];  // [T,B]
  const float* filt  = (const float*)d_in[3];  // [K,1,F]
  const float* wloc  = (const float*)d_in[4];  // [K,A]
  const float* wq    = (const float*)d_in[5];  // [H,A]
  const float* wkp   = (const float*)d_in[6];  // [H,A]
  const float* vvec  = (const float*)d_in[7];  // [A]
  float* out = (float*)d_out;                  // context [B,H] then alignment [T,B]
  float* ws  = (float*)d_ws;

  prep_kernel<<<80, 256, 0, stream>>>(query, filt, wloc, wq, ws);
  score_kernel<<<512, 256, 0, stream>>>(enc, wkp, prev, ws, vvec, ws + WS_SCORE);
  softmax_kernel<<<128, 256, 0, stream>>>(ws + WS_SCORE, out + B_DIM * H_DIM);
  context_partial<<<1024, 256, 0, stream>>>(enc, ws + WS_SCORE, ws + WS_PART);
  context_reduce<<<256, 256, 0, stream>>>(ws + WS_PART, out);
}

// Round 3
// 522.881 us; speedup vs baseline: 1.1350x; 1.1350x over previous
//
#include <hip/hip_runtime.h>
#include <hip/hip_bf16.h>
#include <math.h>

// Problem constants (reference: T,B,H = 1024,128,512; A,K,F = 128,32,31)
#define T_DIM 1024
#define B_DIM 128
#define H_DIM 512
#define A_DIM 128
#define K_DIM 32
#define F_DIM 31

// Workspace layout (float offsets). PART aliases the wk-bf16 region (score
// kernel is done with wk before context runs). Total use = 671744 floats.
#define WS_PQ    0              // [128][128] f32 : query @ W_q
#define WS_SCORE 16384          // [B][T] f32 : scores -> alignment (in-place)
#define WS_WKHI  147456         // [A=128][H=512] u16 : bf16 hi of W_k^T
#define WS_WKLO  180224         // [A=128][H=512] u16 : bf16 lo of W_k^T
#define WS_WCT   212992         // [A=128][32] u16 : bf16 Wcomb^T (f=31 zero-pad)
#define WS_PART  147456         // [8][B][H] f32 : context partials (aliases WKHI+)

typedef __attribute__((ext_vector_type(8)))  short bf16x8;
typedef __attribute__((ext_vector_type(16))) float f32x16;

__device__ __forceinline__ ushort f2bf(float x) {           // f32 -> bf16 RNE
  unsigned u = __float_as_uint(x);
  u += 0x7FFFu + ((u >> 16) & 1u);
  return (ushort)(u >> 16);
}
__device__ __forceinline__ float bf2f(ushort h) {
  return __uint_as_float(((unsigned)h) << 16);
}
__device__ __forceinline__ float fast_tanh(float x) {
  float xc = fminf(10.f, fmaxf(-10.f, x));
  float e2 = __expf(2.f * xc);
  return __fdividef(e2 - 1.f, e2 + 1.f);
}

// ---------------------------------------------------------------------------
// Prep: pq[b][a] (f32, coalesced W_q reads), WcombT bf16 [a][32] (conv x W_loc
// fused, f=31 zeroed), W_k -> transposed bf16 hi/lo [a][h].
// ---------------------------------------------------------------------------
__global__ __launch_bounds__(256) void prep_kernel(
    const float* __restrict__ query, const float* __restrict__ conv_filter,
    const float* __restrict__ W_loc, const float* __restrict__ W_q,
    const float* __restrict__ W_k, float* __restrict__ ws)
{
  int blk = blockIdx.x, tid = threadIdx.x;
  if (blk < 128) {                       // pq for b = blk
    __shared__ float red[256];
    int a = tid & 127, half = tid >> 7;
    const float* q = query + blk * H_DIM + half * 256;
    const float* w = W_q + (size_t)(half * 256) * A_DIM + a;
    float s = 0.f;
    #pragma unroll 8
    for (int h = 0; h < 256; ++h) s = fmaf(q[h], w[(size_t)h * A_DIM], s);
    red[tid] = s;
    __syncthreads();
    if (tid < 128) ws[WS_PQ + blk * A_DIM + tid] = red[tid] + red[tid + 128];
  } else if (blk == 128) {               // WcombT bf16
    ushort* wct = (ushort*)(ws + WS_WCT);
    for (int it = 0; it < 16; ++it) {
      int e = tid + it * 256;            // 0..4095
      int f = e >> 7, a = e & 127;
      float s = 0.f;
      if (f < F_DIM) {
        #pragma unroll
        for (int k = 0; k < K_DIM; ++k)
          s += conv_filter[k * F_DIM + f] * W_loc[k * A_DIM + a];
      }
      wct[a * 32 + f] = f2bf(s);
    }
  } else {                               // W_k -> bf16 hi/lo transposed
    ushort* wkhi = (ushort*)(ws + WS_WKHI);
    ushort* wklo = (ushort*)(ws + WS_WKLO);
    int h0 = (blk - 129) * 16;
    int a = tid & 127, hh = tid >> 7;
    #pragma unroll
    for (int j = 0; j < 8; ++j) {
      int h = h0 + hh * 8 + j;
      float x = W_k[(size_t)h * A_DIM + a];
      ushort hi = f2bf(x);
      float lo = x - bf2f(hi);
      wkhi[a * H_DIM + h] = hi;
      wklo[a * H_DIM + h] = f2bf(lo);
    }
  }
}

// ---------------------------------------------------------------------------
// Score kernel (MFMA split-bf16): block = 256 rows (2 t x 128 b) x 128 a.
//   u = enc@W_k (split bf16, 3 MFMA) + shifted-prev@WcombT (1 MFMA, K-step 17)
//   score[t,b] = sum_a tanh(u + pq[b,a]) * v[a]
// LDS tiles [row][32]bf16, chunk-XOR swizzled; wave tile 64x128, 32x32x16 MFMA.
// ---------------------------------------------------------------------------
__global__ __launch_bounds__(256, 2) void score_kernel(
    const float* __restrict__ enc, const float* __restrict__ ws_f,
    const float* __restrict__ prev, const float* __restrict__ vvec,
    float* __restrict__ score)
{
  __shared__ ushort smA_hi[256 * 32];
  __shared__ ushort smA_lo[256 * 32];
  __shared__ ushort smB_hi[128 * 32];
  __shared__ ushort smB_lo[128 * 32];
  __shared__ float  prevL[32 * 128];

  const ushort* wkhi = (const ushort*)(ws_f + WS_WKHI);
  const ushort* wklo = (const ushort*)(ws_f + WS_WKLO);
  const ushort* wct  = (const ushort*)(ws_f + WS_WCT);
  const float*  pq   = ws_f + WS_PQ;

  const int tid = threadIdx.x;
  const int t0 = blockIdx.x * 2;
  const int R0 = blockIdx.x * 256;       // flat (t*B + b) row base
  const int lane = tid & 63, wv = tid >> 6;
  const int l31 = lane & 31, g = lane >> 5;
  const int wrow = wv * 64;              // wave's 64-row base

  f32x16 acc[2][4];
  #pragma unroll
  for (int mf = 0; mf < 2; ++mf)
    #pragma unroll
    for (int nf = 0; nf < 4; ++nf)
      acc[mf][nf] = (f32x16)(0.f);

  // stage prev rows t0-15 .. t0+16 (zero-padded)
  #pragma unroll
  for (int it = 0; it < 4; ++it) {
    int seg = tid + it * 256;
    int rr = seg >> 5, c4 = (seg & 31) << 2;
    int t = t0 - 15 + rr;
    float4 val = make_float4(0.f, 0.f, 0.f, 0.f);
    if (t >= 0 && t < T_DIM) val = *(const float4*)(prev + t * B_DIM + c4);
    *(float4*)(prevL + rr * 128 + c4) = val;
  }

  // ---- main K loop: 16 chunks of 32 over H ----
  for (int hc = 0; hc < H_DIM; hc += 32) {
    __syncthreads();
    // stage enc rows -> bf16 hi/lo (8 lanes per row, 4 f32 each)
    #pragma unroll
    for (int it = 0; it < 8; ++it) {
      int row = it * 32 + (tid >> 3);
      int sub = tid & 7;
      float4 v = *(const float4*)(enc + (size_t)(R0 + row) * H_DIM + hc + sub * 4);
      ushort4 hi4, lo4;
      hi4.x = f2bf(v.x); lo4.x = f2bf(v.x - bf2f(hi4.x));
      hi4.y = f2bf(v.y); lo4.y = f2bf(v.y - bf2f(hi4.y));
      hi4.z = f2bf(v.z); lo4.z = f2bf(v.z - bf2f(hi4.z));
      hi4.w = f2bf(v.w); lo4.w = f2bf(v.w - bf2f(hi4.w));
      int chunk = sub >> 1;
      int boff = row * 64 + ((chunk ^ ((row >> 1) & 3)) << 4) + ((sub & 1) << 3);
      *(ushort4*)((char*)smA_hi + boff) = hi4;
      *(ushort4*)((char*)smA_lo + boff) = lo4;
    }
    // stage W_k^T bf16 chunk (pure copy, pre-converted by prep)
    #pragma unroll
    for (int it = 0; it < 2; ++it) {
      int a = it * 64 + (tid >> 2);
      int q = tid & 3;
      uint4 vh = *(const uint4*)(wkhi + (size_t)a * H_DIM + hc + q * 8);
      uint4 vl = *(const uint4*)(wklo + (size_t)a * H_DIM + hc + q * 8);
      int boff = a * 64 + ((q ^ ((a >> 1) & 3)) << 4);
      *(uint4*)((char*)smB_hi + boff) = vh;
      *(uint4*)((char*)smB_lo + boff) = vl;
    }
    __syncthreads();
    // MFMA: 2 k-instr x 4 nf x 2 mf x 3 (hi*hi + hi*lo + lo*hi)
    #pragma unroll
    for (int kk = 0; kk < 2; ++kk) {
      bf16x8 ah[2], al[2];
      #pragma unroll
      for (int mf = 0; mf < 2; ++mf) {
        int row = wrow + mf * 32 + l31;
        int boff = row * 64 + (((kk * 2 + g) ^ ((row >> 1) & 3)) << 4);
        ah[mf] = *(const bf16x8*)((const char*)smA_hi + boff);
        al[mf] = *(const bf16x8*)((const char*)smA_lo + boff);
      }
      #pragma unroll
      for (int nf = 0; nf < 4; ++nf) {
        int a = nf * 32 + l31;
        int boff = a * 64 + (((kk * 2 + g) ^ ((a >> 1) & 3)) << 4);
        bf16x8 bh = *(const bf16x8*)((const char*)smB_hi + boff);
        bf16x8 bl = *(const bf16x8*)((const char*)smB_lo + boff);
        #pragma unroll
        for (int mf = 0; mf < 2; ++mf) {
          acc[mf][nf] = __builtin_amdgcn_mfma_f32_32x32x16_bf16(ah[mf], bh, acc[mf][nf], 0, 0, 0);
          acc[mf][nf] = __builtin_amdgcn_mfma_f32_32x32x16_bf16(ah[mf], bl, acc[mf][nf], 0, 0, 0);
          acc[mf][nf] = __builtin_amdgcn_mfma_f32_32x32x16_bf16(al[mf], bh, acc[mf][nf], 0, 0, 0);
        }
      }
    }
  }

  // ---- K-step 17: location term via plain-bf16 MFMA ----
  __syncthreads();
  {
    // A' : [row][f] = prev[t(row)-15+f, b(row)], f=31 zero
    int trow = tid >> 7, bcol = tid & 127;
    #pragma unroll
    for (int q = 0; q < 4; ++q) {
      bf16x8 pk;
      #pragma unroll
      for (int e = 0; e < 8; ++e) {
        int f = q * 8 + e;
        float pv = (f < F_DIM) ? prevL[(trow + f) * 128 + bcol] : 0.f;
        pk[e] = (short)f2bf(pv);
      }
      int boff = tid * 64 + ((q ^ ((tid >> 1) & 3)) << 4);
      *(bf16x8*)((char*)smA_hi + boff) = pk;
    }
    // B' : WcombT
    #pragma unroll
    for (int it = 0; it < 2; ++it) {
      int a = it * 64 + (tid >> 2);
      int q = tid & 3;
      uint4 vv = *(const uint4*)(wct + a * 32 + q * 8);
      *(uint4*)((char*)smB_hi + a * 64 + ((q ^ ((a >> 1) & 3)) << 4)) = vv;
    }
  }
  __syncthreads();
  #pragma unroll
  for (int kk = 0; kk < 2; ++kk) {
    bf16x8 ah[2];
    #pragma unroll
    for (int mf = 0; mf < 2; ++mf) {
      int row = wrow + mf * 32 + l31;
      int boff = row * 64 + (((kk * 2 + g) ^ ((row >> 1) & 3)) << 4);
      ah[mf] = *(const bf16x8*)((const char*)smA_hi + boff);
    }
    #pragma unroll
    for (int nf = 0; nf < 4; ++nf) {
      int a = nf * 32 + l31;
      int boff = a * 64 + (((kk * 2 + g) ^ ((a >> 1) & 3)) << 4);
      bf16x8 bh = *(const bf16x8*)((const char*)smB_hi + boff);
      #pragma unroll
      for (int mf = 0; mf < 2; ++mf)
        acc[mf][nf] = __builtin_amdgcn_mfma_f32_32x32x16_bf16(ah[mf], bh, acc[mf][nf], 0, 0, 0);
    }
  }

  // ---- epilogue: + pq, tanh, dot v, 32-lane reduce, write score[b][t] ----
  float vval[4];
  #pragma unroll
  for (int nf = 0; nf < 4; ++nf) vval[nf] = vvec[nf * 32 + l31];
  #pragma unroll
  for (int mf = 0; mf < 2; ++mf) {
    #pragma unroll
    for (int reg = 0; reg < 16; ++reg) {
      int row = wrow + mf * 32 + (reg & 3) + 8 * (reg >> 2) + 4 * g;
      int b = row & 127;
      float s = 0.f;
      #pragma unroll
      for (int nf = 0; nf < 4; ++nf) {
        float u = acc[mf][nf][reg] + pq[b * A_DIM + nf * 32 + l31];
        s = fmaf(fast_tanh(u), vval[nf], s);
      }
      s += __shfl_xor(s, 1); s += __shfl_xor(s, 2); s += __shfl_xor(s, 4);
      s += __shfl_xor(s, 8); s += __shfl_xor(s, 16);
      if (l31 == 0) {
        int t = t0 + (row >> 7);
        score[b * T_DIM + t] = s;
      }
    }
  }
}

// ---------------------------------------------------------------------------
// Softmax over t per batch b; alignment in-place ([B][T]) + d_out ([T][B]).
// ---------------------------------------------------------------------------
__global__ __launch_bounds__(256) void softmax_kernel(
    float* __restrict__ score, float* __restrict__ out_align)
{
  __shared__ float red[8];
  int b = blockIdx.x, tid = threadIdx.x;
  float v0[4];
  #pragma unroll
  for (int i = 0; i < 4; ++i) v0[i] = score[b * T_DIM + tid + i * 256];
  float m = fmaxf(fmaxf(v0[0], v0[1]), fmaxf(v0[2], v0[3]));
  #pragma unroll
  for (int off = 1; off < 64; off <<= 1) m = fmaxf(m, __shfl_xor(m, off));
  if ((tid & 63) == 0) red[tid >> 6] = m;
  __syncthreads();
  m = fmaxf(fmaxf(red[0], red[1]), fmaxf(red[2], red[3]));
  float s = 0.f;
  #pragma unroll
  for (int i = 0; i < 4; ++i) { v0[i] = expf(v0[i] - m); s += v0[i]; }
  #pragma unroll
  for (int off = 1; off < 64; off <<= 1) s += __shfl_xor(s, off);
  if ((tid & 63) == 0) red[4 + (tid >> 6)] = s;
  __syncthreads();
  float inv = 1.f / (red[4] + red[5] + red[6] + red[7]);
  #pragma unroll
  for (int i = 0; i < 4; ++i) {
    float a = v0[i] * inv;
    int t = tid + i * 256;
    score[b * T_DIM + t] = a;
    out_align[t * B_DIM + b] = a;
  }
}

// ---------------------------------------------------------------------------
// Context: partial[tc][b][h] = sum_{t in chunk} align[t,b]*enc[t,b,h].
// 4-deep independent load chains to hide HBM latency.
// ---------------------------------------------------------------------------
__global__ __launch_bounds__(256) void context_partial(
    const float* __restrict__ enc, const float* __restrict__ align_bt,
    float* __restrict__ partial)
{
  int b  = blockIdx.x >> 3;
  int tc = blockIdx.x & 7;
  int tid = threadIdx.x;
  const float* ab = align_bt + b * T_DIM + tc * 128;
  const float* eb = enc + ((size_t)(tc * 128) * B_DIM + b) * H_DIM + tid * 2;
  const size_t stride = (size_t)B_DIM * H_DIM;
  float2 a0 = {0.f, 0.f}, a1 = {0.f, 0.f}, a2 = {0.f, 0.f}, a3 = {0.f, 0.f};
  for (int t = 0; t < 128; t += 4) {
    float4 av = *(const float4*)(ab + t);
    float2 e0 = *(const float2*)(eb + (size_t)(t + 0) * stride);
    float2 e1 = *(const float2*)(eb + (size_t)(t + 1) * stride);
    float2 e2 = *(const float2*)(eb + (size_t)(t + 2) * stride);
    float2 e3 = *(const float2*)(eb + (size_t)(t + 3) * stride);
    a0.x = fmaf(av.x, e0.x, a0.x); a0.y = fmaf(av.x, e0.y, a0.y);
    a1.x = fmaf(av.y, e1.x, a1.x); a1.y = fmaf(av.y, e1.y, a1.y);
    a2.x = fmaf(av.z, e2.x, a2.x); a2.y = fmaf(av.z, e2.y, a2.y);
    a3.x = fmaf(av.w, e3.x, a3.x); a3.y = fmaf(av.w, e3.y, a3.y);
  }
  float2 r;
  r.x = (a0.x + a1.x) + (a2.x + a3.x);
  r.y = (a0.y + a1.y) + (a2.y + a3.y);
  *(float2*)(partial + ((size_t)tc * B_DIM + b) * H_DIM + tid * 2) = r;
}

__global__ __launch_bounds__(256) void context_reduce(
    const float* __restrict__ partial, float* __restrict__ ctx)
{
  int idx = blockIdx.x * 256 + threadIdx.x;
  float s = 0.f;
  #pragma unroll
  for (int tc = 0; tc < 8; ++tc) s += partial[tc * (B_DIM * H_DIM) + idx];
  ctx[idx] = s;
}

// ---------------------------------------------------------------------------
extern "C" void kernel_launch(void* const* d_in, const int* in_sizes, int n_in,
                              void* d_out, int out_size, void* d_ws, size_t ws_size,
                              hipStream_t stream)
{
  const float* enc   = (const float*)d_in[0];  // [T,B,H]
  const float* query = (const float*)d_in[1];  // [B,H]
  const float* prev  = (const float*)d_in[2];  // [T,B]
  const float* filt  = (const float*)d_in[3];  // [K,1,F]
  const float* wloc  = (const float*)d_in[4];  // [K,A]
  const float* wq    = (const float*)d_in[5];  // [H,A]
  const float* wkp   = (const float*)d_in[6];  // [H,A]
  const float* vvec  = (const float*)d_in[7];  // [A]
  float* out = (float*)d_out;                  // context [B,H] then alignment [T,B]
  float* ws  = (float*)d_ws;

  prep_kernel<<<161, 256, 0, stream>>>(query, filt, wloc, wq, wkp, ws);
  score_kernel<<<512, 256, 0, stream>>>(enc, ws, prev, vvec, ws + WS_SCORE);
  softmax_kernel<<<128, 256, 0, stream>>>(ws + WS_SCORE, out + B_DIM * H_DIM);
  context_partial<<<1024, 256, 0, stream>>>(enc, ws + WS_SCORE, ws + WS_PART);
  context_reduce<<<256, 256, 0, stream>>>(ws + WS_PART, out);
}